// Round 7
// baseline (327.080 us; speedup 1.0000x reference)
//
#include <hip/hip_runtime.h>
#include <hip/hip_bf16.h>

// B=2, S=2048, HID=2048, NH=16, HD=128.
// cast->bf16, QKV GEMM (BM256xBN128xBK64, 3-buffer depth-2 counted-vmcnt
// pipeline), rope tables, rope+rmsnorm (in-place), flash attention
// (k-parity-split 8-wave blocks, defer-max exp2 softmax, sigma-permuted PV),
// projection GEMM (fp32 out). Grids are exact multiples of 256 CUs.

typedef __attribute__((ext_vector_type(8))) short short8_t;   // 8 x bf16
typedef __attribute__((ext_vector_type(4))) short short4_t;
typedef __attribute__((ext_vector_type(4))) float f32x4;

#define S_LEN 2048
#define NHEAD 16
#define HDIM  128
#define HID   2048
#define MROWS 4096            // B*S
#define SCALEF 0.08838834764831845f

__device__ __forceinline__ float bf2f(ushort u) {
  union { unsigned int u; float f; } a; a.u = ((unsigned int)u) << 16; return a.f;
}
__device__ __forceinline__ ushort f2bf(float f) {
  union { float f; unsigned int u; } a; a.f = f;
  unsigned int r = a.u + 0x7FFFu + ((a.u >> 16) & 1u);
  return (ushort)(r >> 16);
}
__device__ __forceinline__ void store_out(ushort* p, float v) { *p = f2bf(v); }
__device__ __forceinline__ void store_out(float* p, float v) { *p = v; }

// async global->LDS, 16B per lane; LDS dest must be wave-uniform (HW adds lane*16).
__device__ __forceinline__ void gload_lds16(const void* g, void* l) {
  __builtin_amdgcn_global_load_lds(
      (const __attribute__((address_space(1))) unsigned int*)g,
      (__attribute__((address_space(3))) unsigned int*)l, 16, 0, 0);
}

// ---------------------------------------------------------------- casts
__global__ __launch_bounds__(256) void cast_bf16_kernel(
    const float* __restrict__ in, ushort* __restrict__ out, int n4) {
  int i = blockIdx.x * 256 + threadIdx.x;
  const int stride = gridDim.x * 256;
  for (; i < n4; i += stride) {
    float4 v = ((const float4*)in)[i];
    short4_t o = { (short)f2bf(v.x), (short)f2bf(v.y),
                   (short)f2bf(v.z), (short)f2bf(v.w) };
    ((short4_t*)out)[i] = o;
  }
}

// ---------------------------------------------------------------- rope tables
__global__ __launch_bounds__(256) void rope_tab_kernel(
    float* __restrict__ cosT, float* __restrict__ sinT) {
  int idx = blockIdx.x * 256 + threadIdx.x;
  if (idx >= S_LEN * 64) return;
  int s = idx >> 6, i = idx & 63;
  float f = expf(9.2103403719761836f * (float)(2 * i));
  float inv = 1.0f / f;                 // inf -> 0, matches reference
  float ang = (float)s * inv;
  cosT[idx] = cosf(ang);
  sinT[idx] = sinf(ang);
}

// ---------------------------------------------------------------- pipelined GEMM
// (unchanged from round 6 — BM=256 x BN=128, BK=64, 3 buffers, depth-2
// counted vmcnt, conflict-free XOR swizzle, 0 bank conflicts measured)
#define RD_FRAGS(KK) \
  _Pragma("unroll") for (int j = 0; j < 4; ++j) { \
    const int rw = wn * 64 + j * 16 + lq; \
    bfr[j] = *(const short8_t*)(bufp + ABYTES + rw * 128 + \
                                ((((KK) * 4 + lg) ^ (rw & 7)) << 4)); } \
  _Pragma("unroll") for (int i = 0; i < 4; ++i) { \
    const int rw = wm * 64 + i * 16 + lq; \
    af[i] = *(const short8_t*)(bufp + rw * 128 + \
                               ((((KK) * 4 + lg) ^ (rw & 7)) << 4)); }
#define MFMA_ALL() _Pragma("unroll") for (int i = 0; i < 4; ++i) \
    _Pragma("unroll") for (int j = 0; j < 4; ++j) \
      acc[i][j] = __builtin_amdgcn_mfma_f32_16x16x32_bf16( \
          af[i], bfr[j], acc[i][j], 0, 0, 0);
#define MID_SYNC() \
    __builtin_amdgcn_s_barrier(); \
    asm volatile("s_waitcnt lgkmcnt(0)" ::: "memory"); \
    __builtin_amdgcn_sched_barrier(0); \
    __builtin_amdgcn_s_setprio(1);
#define END_PHASE() \
    __builtin_amdgcn_s_setprio(0);

template <typename OutT>
__global__ __launch_bounds__(512, 2) void gemm_pipe_kernel(
    const ushort* __restrict__ A, const ushort* __restrict__ W,
    OutT* __restrict__ C, int M, int N, int K) {
  constexpr int ABYTES = 32768;           // A bytes per buffer (256 x 128B)
  constexpr int BUF = 49152;              // A + B (128 x 128B)
  __shared__ __align__(16) char lds[3 * BUF];   // 147456 B

  const int n0 = blockIdx.x * 128;
  const int m0 = blockIdx.y * 256;
  const ushort* Wz = W + (size_t)blockIdx.z * N * K;
  OutT* Cz = C + (size_t)blockIdx.z * M * N;

  const int tid = threadIdx.x;
  const int lane = tid & 63, wid = tid >> 6;
  const int lq = lane & 15, lg = lane >> 4;
  const int wm = wid >> 1, wn = wid & 1;
  const int NT = K >> 6;                  // BK = 64
  const int wb = wid * 1024;              // wave-uniform LDS byte base per call

  const int strow = tid >> 3;             // 0..63
  const int sc8 = (((tid & 7) ^ (strow & 7)) << 3);   // element col 0..56
  const ushort* pa = A + (size_t)(m0 + strow) * K + sc8;
  const ushort* pw = Wz + (size_t)(n0 + strow) * K + sc8;

#define STG_P0(BI, KC) { \
    gload_lds16(pa + (KC), lds + (BI) * BUF + wb); \
    gload_lds16(pa + (size_t)64 * K + (KC), lds + (BI) * BUF + 8192 + wb); \
    gload_lds16(pw + (KC), lds + (BI) * BUF + ABYTES + wb); }
#define STG_P1(BI, KC) { \
    gload_lds16(pa + (size_t)128 * K + (KC), lds + (BI) * BUF + 16384 + wb); \
    gload_lds16(pa + (size_t)192 * K + (KC), lds + (BI) * BUF + 24576 + wb); \
    gload_lds16(pw + (size_t)64 * K + (KC), lds + (BI) * BUF + ABYTES + 8192 + wb); }

  f32x4 acc[4][4];
#pragma unroll
  for (int i = 0; i < 4; i++)
#pragma unroll
    for (int j = 0; j < 4; j++) acc[i][j] = (f32x4){0.f, 0.f, 0.f, 0.f};

  STG_P0(0, 0); STG_P1(0, 0);
  STG_P0(1, 64); STG_P1(1, 64);
  asm volatile("s_waitcnt vmcnt(6)" ::: "memory");
  __builtin_amdgcn_s_barrier();
  __builtin_amdgcn_sched_barrier(0);

  int b = 0, b2 = 2;                      // t%3 and (t+2)%3
  for (int t = 0; t < NT; ++t) {
    const int kc2 = (t + 2) << 6;
    const bool st = (t + 2 < NT);
    const char* bufp = lds + b * BUF;
    short8_t af[4], bfr[4];

    RD_FRAGS(0);
    if (st) STG_P0(b2, kc2);
    MID_SYNC();
    MFMA_ALL();
    END_PHASE();
    __builtin_amdgcn_s_barrier();
    __builtin_amdgcn_sched_barrier(0);

    RD_FRAGS(1);
    if (st) STG_P1(b2, kc2);
    MID_SYNC();
    MFMA_ALL();
    END_PHASE();
    if (st) asm volatile("s_waitcnt vmcnt(6)" ::: "memory");
    else    asm volatile("s_waitcnt vmcnt(0)" ::: "memory");
    __builtin_amdgcn_s_barrier();
    __builtin_amdgcn_sched_barrier(0);
    b = (b == 2) ? 0 : b + 1;
    b2 = (b2 == 2) ? 0 : b2 + 1;
  }

#pragma unroll
  for (int mi = 0; mi < 4; mi++) {
#pragma unroll
    for (int r = 0; r < 4; r++) {
      const int m = m0 + wm * 64 + mi * 16 + lg * 4 + r;
      OutT* cp = Cz + (size_t)m * N + n0 + wn * 64 + lq;
#pragma unroll
      for (int j = 0; j < 4; j++) store_out(cp + j * 16, acc[mi][j][r]);
    }
  }
}

// ---------------------------------------------------------------- RoPE + RMSNorm
__global__ __launch_bounds__(256) void rope_norm_kernel(
    const ushort* __restrict__ in, ushort* __restrict__ out,
    const float* __restrict__ nw, const float* __restrict__ cosT,
    const float* __restrict__ sinT) {
  const int w = threadIdx.x >> 6, lane = threadIdx.x & 63;
  const int rid = blockIdx.x * 4 + w;          // (b*S+s)*NH + h
  const int s = (rid >> 4) & (S_LEN - 1);
  const size_t off = (size_t)rid * HDIM;
  float x1 = bf2f(in[off + lane]);
  float x2 = bf2f(in[off + 64 + lane]);
  float c = cosT[s * 64 + lane], sn = sinT[s * 64 + lane];
  float y1 = x1 * c - x2 * sn;
  float y2 = x2 * c + x1 * sn;
  float ss = y1 * y1 + y2 * y2;
#pragma unroll
  for (int m = 1; m < 64; m <<= 1) ss += __shfl_xor(ss, m, 64);
  float sc = rsqrtf(ss * (1.f / 128.f) + 1e-6f);
  out[off + lane] = f2bf(y1 * sc * nw[lane]);
  out[off + 64 + lane] = f2bf(y2 * sc * nw[lane + 64]);
}

// ---------------------------------------------------------------- flash attention
// Grid = 512 blocks: (b, h, j), q-tile pair {j, 31-j}. Block = 512 threads =
// 8 waves: 4 q-groups (16 rows) x 2 k-parities. Parity p handles chunks 2i+p
// in its own KV LDS region -> exactly 33 chunk-iterations per wave for EVERY
// block (balance) and 16 waves/CU (2 blocks/CU resident).
// Softmax in exp2 space (scores pre-scaled by SCALE*log2e), T13 defer-max
// (skip o-rescale when chunk max within 11.0 of running max). End-of-tile
// cross-parity (m,l,o) merge via LDS overlay; parity 0 writes O.
__global__ __launch_bounds__(512, 4) void attn_kernel(
    const ushort* __restrict__ Q, const ushort* __restrict__ K,
    const ushort* __restrict__ V, ushort* __restrict__ O) {
  __shared__ __align__(16) char LB[34816];   // 2 x 17408 KV; merge overlays

  const int bid = blockIdx.x;
  const int jj = bid & 15;
  const int h  = (bid >> 4) & 15;
  const int b  = bid >> 8;
  const int tid = threadIdx.x;
  const int lane = tid & 63, wid = tid >> 6;
  const int g  = wid & 3;            // q-group
  const int pr = wid >> 2;           // k-parity
  const int lq = lane & 15, lg = lane >> 4;

  char* KV  = LB + pr * 17408;
  char* Ksb = KV;                       // 32x128 bf16, XOR-swizzled rows
  uint* Vt32 = (uint*)(KV + 8192);      // [128][18] packed k-pairs
  float* mB = (float*)LB;               // [4][16]   (merge overlay)
  float* lB = (float*)(LB + 256);       // [4][16]
  float* oB = (float*)(LB + 512);       // [4][16][132]

  // K staging (per parity group: 4 waves x 2 gloads = 32 rows; rule-21 src swz)
  const int krow0 = g * 8 + (lane >> 4);
  const int krow1 = krow0 + 4;
  const int kc0 = ((lane & 15) * 16) ^ ((krow0 & 7) << 4);
  const int kc1 = ((lane & 15) * 16) ^ ((krow1 & 7) << 4);
  // V staging (256 threads per parity group)
  const int t4 = tid & 255;
  const int vp  = t4 & 15;
  const int vd0 = (t4 >> 4) * 8;
  const int vc  = (vp < 8) ? ((vp >> 1) * 4 + (vp & 1))
                           : (((vp - 8) >> 1) * 4 + 2 + (vp & 1));

  const float CL2 = 0.12753102368f;     // SCALEF * log2(e)

  for (int t = 0; t < 2; t++) {
    const int qt = t ? (31 - jj) : jj;
    const int q0 = qt * 64 + g * 16;

    const ushort* qp = Q + (size_t)(b * S_LEN + q0 + lq) * HID + h * HDIM + lg * 8;
    short8_t qf[4];
#pragma unroll
    for (int dc = 0; dc < 4; dc++) qf[dc] = *(const short8_t*)(qp + dc * 32);

    f32x4 o[8];
#pragma unroll
    for (int i = 0; i < 8; i++) o[i] = (f32x4){0.f, 0.f, 0.f, 0.f};
    float m_run = -1e30f, l_run = 0.f;
    const int qlim = q0 + 15;
    const int NI = qt + 1;              // chunk pairs for this tile

    for (int i = 0; i < NI; ++i) {
      const int k0 = (2 * i + pr) * 32;
      __syncthreads();
      {
        const size_t kbase = (size_t)(b * S_LEN + k0) * HID + h * HDIM;
        gload_lds16(K + kbase + (size_t)krow0 * HID + (kc0 >> 1), Ksb + g * 2048);
        gload_lds16(K + kbase + (size_t)krow1 * HID + (kc1 >> 1), Ksb + g * 2048 + 1024);
        const ushort* vsrc = V + kbase + (size_t)(2 * vp) * HID + vd0;
        short8_t va = *(const short8_t*)vsrc;
        short8_t vb = *(const short8_t*)(vsrc + HID);
#pragma unroll
        for (int e = 0; e < 8; e++)
          Vt32[(vd0 + e) * 18 + vc] =
              (uint)(ushort)va[e] | ((uint)(ushort)vb[e] << 16);
      }
      __syncthreads();
      if (k0 > qlim) continue;          // fully-masked chunk for this wave

      // S^T = K-chunk @ Q^T
      f32x4 st0 = (f32x4){0.f, 0.f, 0.f, 0.f};
      f32x4 st1 = (f32x4){0.f, 0.f, 0.f, 0.f};
#pragma unroll
      for (int dc = 0; dc < 4; dc++) {
        const int row0 = lq, row1 = 16 + lq;
        short8_t kf0 = *(const short8_t*)(Ksb + ((row0 * 256 + dc * 64 + lg * 16) ^ ((row0 & 7) << 4)));
        short8_t kf1 = *(const short8_t*)(Ksb + ((row1 * 256 + dc * 64 + lg * 16) ^ ((row1 & 7) << 4)));
        st0 = __builtin_amdgcn_mfma_f32_16x16x32_bf16(kf0, qf[dc], st0, 0, 0, 0);
        st1 = __builtin_amdgcn_mfma_f32_16x16x32_bf16(kf1, qf[dc], st1, 0, 0, 0);
      }

      const int qg = q0 + lq;
      float sv[8]; float mx = -1e30f;
#pragma unroll
      for (int r = 0; r < 4; r++) {
        const int kk0 = k0 + lg * 4 + r;
        const int kk1 = kk0 + 16;
        float v0 = (kk0 <= qg) ? st0[r] * CL2 : -1e30f;
        float v1 = (kk1 <= qg) ? st1[r] * CL2 : -1e30f;
        sv[r] = v0; sv[4 + r] = v1;
        mx = fmaxf(mx, fmaxf(v0, v1));
      }
      mx = fmaxf(mx, __shfl_xor(mx, 16, 64));
      mx = fmaxf(mx, __shfl_xor(mx, 32, 64));

      float p[8]; float ps = 0.f;
      if (__all(mx <= m_run + 11.0f)) {
        // deferred: keep old max, no o-rescale (P bounded by 2^11, bf16-safe)
#pragma unroll
        for (int u = 0; u < 8; u++) { p[u] = exp2f(sv[u] - m_run); ps += p[u]; }
        ps += __shfl_xor(ps, 16, 64);
        ps += __shfl_xor(ps, 32, 64);
        l_run += ps;
      } else {
        const float m_new = fmaxf(m_run, mx);
        const float alpha = exp2f(m_run - m_new);
#pragma unroll
        for (int u = 0; u < 8; u++) { p[u] = exp2f(sv[u] - m_new); ps += p[u]; }
        ps += __shfl_xor(ps, 16, 64);
        ps += __shfl_xor(ps, 32, 64);
        l_run = l_run * alpha + ps;
        m_run = m_new;
#pragma unroll
        for (int r = 0; r < 4; r++) {
          const float ar = __shfl(alpha, lg * 4 + r, 64);
#pragma unroll
          for (int nt = 0; nt < 8; nt++) o[nt][r] *= ar;
        }
      }

      union { uint u[4]; short8_t s; } pu;
      pu.u[0] = (uint)f2bf(p[0]) | ((uint)f2bf(p[1]) << 16);
      pu.u[1] = (uint)f2bf(p[2]) | ((uint)f2bf(p[3]) << 16);
      pu.u[2] = (uint)f2bf(p[4]) | ((uint)f2bf(p[5]) << 16);
      pu.u[3] = (uint)f2bf(p[6]) | ((uint)f2bf(p[7]) << 16);
      const short8_t pa = pu.s;

#pragma unroll
      for (int nt = 0; nt < 8; nt++) {
        const uint* vq = &Vt32[(nt * 16 + lq) * 18 + lg * 4];
        uint2 vlo = *(const uint2*)vq;
        uint2 vhi = *(const uint2*)(vq + 2);
        union { uint u[4]; short8_t s; } vu;
        vu.u[0] = vlo.x; vu.u[1] = vlo.y; vu.u[2] = vhi.x; vu.u[3] = vhi.y;
        o[nt] = __builtin_amdgcn_mfma_f32_16x16x32_bf16(pa, vu.s, o[nt], 0, 0, 0);
      }
    }

    // ---- cross-parity merge (overlays KV region; barrier-separated) ----
    __syncthreads();
    if (pr == 1) {
      if (lane < 16) { mB[g * 16 + lane] = m_run; lB[g * 16 + lane] = l_run; }
#pragma unroll
      for (int r = 0; r < 4; r++)
#pragma unroll
        for (int nt = 0; nt < 8; nt++)
          oB[g * 2112 + (lg * 4 + r) * 132 + nt * 16 + lq] = o[nt][r];
    }
    __syncthreads();
    if (pr == 0) {
      const float mBv = mB[g * 16 + lq];
      const float lBv = lB[g * 16 + lq];
      const float mM = fmaxf(m_run, mBv);
      const float fA = exp2f(m_run - mM);
      const float fBv = exp2f(mBv - mM);
      const float lM = l_run * fA + lBv * fBv;
      const float invl = (lM > 0.f) ? 1.f / lM : 0.f;
#pragma unroll
      for (int r = 0; r < 4; r++) {
        const float faq = __shfl(fA, lg * 4 + r, 64);
        const float fbq = __shfl(fBv, lg * 4 + r, 64);
        const float ivq = __shfl(invl, lg * 4 + r, 64);
        ushort* op = O + (size_t)(b * S_LEN + q0 + lg * 4 + r) * HID + h * HDIM + lq;
#pragma unroll
        for (int nt = 0; nt < 8; nt++) {
          const float ov = oB[g * 2112 + (lg * 4 + r) * 132 + nt * 16 + lq];
          op[nt * 16] = f2bf((o[nt][r] * faq + ov * fbq) * ivq);
        }
      }
    }
    // next tile's loop-top __syncthreads protects the merge-region reuse
  }
}

// ---------------------------------------------------------------- launcher
extern "C" void kernel_launch(void* const* d_in, const int* in_sizes, int n_in,
                              void* d_out, int out_size, void* d_ws, size_t ws_size,
                              hipStream_t stream) {
  const float* x   = (const float*)d_in[0];
  const float* wq  = (const float*)d_in[1];
  const float* wk  = (const float*)d_in[2];
  const float* wv  = (const float*)d_in[3];
  const float* wo  = (const float*)d_in[4];
  const float* qnw = (const float*)d_in[5];
  const float* knw = (const float*)d_in[6];
  float* out = (float*)d_out;
  char* ws = (char*)d_ws;

  const size_t NELEM = (size_t)MROWS * HID;       // 8388608
  const size_t WELEM = (size_t)HID * HID;         // 4194304

  ushort* xb    = (ushort*)(ws);                          // 16777216 B
  ushort* wqkvb = (ushort*)(ws + 16777216);               // 25165824 B
  ushort* wob   = (ushort*)(ws + 41943040);               //  8388608 B
  ushort* qkv   = (ushort*)(ws + 50331648);               // 50331648 B (q,k,v)
  float*  cosT  = (float*)(ws + 100663296);               //   524288 B
  float*  sinT  = (float*)(ws + 101187584);               //   524288 B
  ushort* attnb = xb;                                     // alias (xb dead after QKV)

  cast_bf16_kernel<<<1024, 256, 0, stream>>>(x, xb, (int)(NELEM / 4));
  cast_bf16_kernel<<<1024, 256, 0, stream>>>(wq, wqkvb, (int)(WELEM / 4));
  cast_bf16_kernel<<<1024, 256, 0, stream>>>(wk, wqkvb + WELEM, (int)(WELEM / 4));
  cast_bf16_kernel<<<1024, 256, 0, stream>>>(wv, wqkvb + 2 * WELEM, (int)(WELEM / 4));
  cast_bf16_kernel<<<1024, 256, 0, stream>>>(wo, wob, (int)(WELEM / 4));
  rope_tab_kernel<<<512, 256, 0, stream>>>(cosT, sinT);

  // QKV = x @ {wq,wk,wv}^T (bf16 out): BM=256 x BN=128, 768 blocks = 3x256 CUs
  gemm_pipe_kernel<ushort><<<dim3(16, 16, 3), 512, 0, stream>>>(
      xb, wqkvb, qkv, MROWS, HID, HID);

  rope_norm_kernel<<<16384, 256, 0, stream>>>(qkv, qkv, qnw, cosT, sinT);
  rope_norm_kernel<<<16384, 256, 0, stream>>>(qkv + NELEM, qkv + NELEM, knw, cosT, sinT);

  // attention: 512 blocks x 512 threads (8 waves: 4 q-groups x 2 k-parities)
  attn_kernel<<<512, 512, 0, stream>>>(qkv, qkv + NELEM, qkv + 2 * NELEM, attnb);

  // out = attn @ wo^T (fp32 out): 256 blocks = 1x256 CUs
  gemm_pipe_kernel<float><<<dim3(16, 16, 1), 512, 0, stream>>>(
      attnb, wob, out, MROWS, HID, HID);
}

// Round 8
// 314.570 us; speedup vs baseline: 1.0398x; 1.0398x over previous
//
#include <hip/hip_runtime.h>
#include <hip/hip_bf16.h>

// B=2, S=2048, HID=2048, NH=16, HD=128.
// fused cast->bf16, QKV GEMM (BM256xBN128xBK64, 3-buffer depth-2 counted-vmcnt
// pipeline), rope tables, fused rope+rmsnorm (in-place), flash attention
// (4-wave blocks, double-buffered KV prefetch, XCD-grouped heads, defer-max
// exp2 softmax, sigma-permuted PV), projection GEMM (fp32 out).

typedef __attribute__((ext_vector_type(8))) short short8_t;   // 8 x bf16
typedef __attribute__((ext_vector_type(4))) short short4_t;
typedef __attribute__((ext_vector_type(4))) float f32x4;

#define S_LEN 2048
#define NHEAD 16
#define HDIM  128
#define HID   2048
#define MROWS 4096            // B*S
#define SCALEF 0.08838834764831845f

__device__ __forceinline__ float bf2f(ushort u) {
  union { unsigned int u; float f; } a; a.u = ((unsigned int)u) << 16; return a.f;
}
__device__ __forceinline__ ushort f2bf(float f) {
  union { float f; unsigned int u; } a; a.f = f;
  unsigned int r = a.u + 0x7FFFu + ((a.u >> 16) & 1u);
  return (ushort)(r >> 16);
}
__device__ __forceinline__ void store_out(ushort* p, float v) { *p = f2bf(v); }
__device__ __forceinline__ void store_out(float* p, float v) { *p = v; }

// async global->LDS, 16B per lane; LDS dest must be wave-uniform (HW adds lane*16).
__device__ __forceinline__ void gload_lds16(const void* g, void* l) {
  __builtin_amdgcn_global_load_lds(
      (const __attribute__((address_space(1))) unsigned int*)g,
      (__attribute__((address_space(3))) unsigned int*)l, 16, 0, 0);
}

// ---------------------------------------------------------------- fused casts
// segments in float4 units: x 2097152 | wq 1048576 | wk | wv | wo
__global__ __launch_bounds__(256) void cast_all_kernel(
    const float* __restrict__ x, const float* __restrict__ wq,
    const float* __restrict__ wk, const float* __restrict__ wv,
    const float* __restrict__ wo, ushort* __restrict__ xb,
    ushort* __restrict__ wqkvb, ushort* __restrict__ wob) {
  int i = blockIdx.x * 256 + threadIdx.x;
  const int stride = gridDim.x * 256;
  for (; i < 6291456; i += stride) {
    const float4* src; short4_t* dst; int off;
    if (i < 2097152)      { src = (const float4*)x;  dst = (short4_t*)xb;               off = i; }
    else if (i < 3145728) { src = (const float4*)wq; dst = (short4_t*)wqkvb;            off = i - 2097152; }
    else if (i < 4194304) { src = (const float4*)wk; dst = (short4_t*)wqkvb + 1048576;  off = i - 3145728; }
    else if (i < 5242880) { src = (const float4*)wv; dst = (short4_t*)wqkvb + 2097152;  off = i - 4194304; }
    else                  { src = (const float4*)wo; dst = (short4_t*)wob;              off = i - 5242880; }
    float4 v = src[off];
    short4_t o = { (short)f2bf(v.x), (short)f2bf(v.y),
                   (short)f2bf(v.z), (short)f2bf(v.w) };
    dst[off] = o;
  }
}

// ---------------------------------------------------------------- rope tables
__global__ __launch_bounds__(256) void rope_tab_kernel(
    float* __restrict__ cosT, float* __restrict__ sinT) {
  int idx = blockIdx.x * 256 + threadIdx.x;
  if (idx >= S_LEN * 64) return;
  int s = idx >> 6, i = idx & 63;
  float f = expf(9.2103403719761836f * (float)(2 * i));
  float inv = 1.0f / f;                 // inf -> 0, matches reference
  float ang = (float)s * inv;
  cosT[idx] = cosf(ang);
  sinT[idx] = sinf(ang);
}

// ---------------------------------------------------------------- pipelined GEMM
// (unchanged round-6 winner: BM=256 x BN=128, BK=64, 3 buffers, depth-2
// counted vmcnt, conflict-free XOR swizzle — 0 bank conflicts measured)
#define RD_FRAGS(KK) \
  _Pragma("unroll") for (int j = 0; j < 4; ++j) { \
    const int rw = wn * 64 + j * 16 + lq; \
    bfr[j] = *(const short8_t*)(bufp + ABYTES + rw * 128 + \
                                ((((KK) * 4 + lg) ^ (rw & 7)) << 4)); } \
  _Pragma("unroll") for (int i = 0; i < 4; ++i) { \
    const int rw = wm * 64 + i * 16 + lq; \
    af[i] = *(const short8_t*)(bufp + rw * 128 + \
                               ((((KK) * 4 + lg) ^ (rw & 7)) << 4)); }
#define MFMA_ALL() _Pragma("unroll") for (int i = 0; i < 4; ++i) \
    _Pragma("unroll") for (int j = 0; j < 4; ++j) \
      acc[i][j] = __builtin_amdgcn_mfma_f32_16x16x32_bf16( \
          af[i], bfr[j], acc[i][j], 0, 0, 0);
#define MID_SYNC() \
    __builtin_amdgcn_s_barrier(); \
    asm volatile("s_waitcnt lgkmcnt(0)" ::: "memory"); \
    __builtin_amdgcn_sched_barrier(0); \
    __builtin_amdgcn_s_setprio(1);
#define END_PHASE() \
    __builtin_amdgcn_s_setprio(0);

template <typename OutT>
__global__ __launch_bounds__(512, 2) void gemm_pipe_kernel(
    const ushort* __restrict__ A, const ushort* __restrict__ W,
    OutT* __restrict__ C, int M, int N, int K) {
  constexpr int ABYTES = 32768;           // A bytes per buffer (256 x 128B)
  constexpr int BUF = 49152;              // A + B (128 x 128B)
  __shared__ __align__(16) char lds[3 * BUF];   // 147456 B

  const int n0 = blockIdx.x * 128;
  const int m0 = blockIdx.y * 256;
  const ushort* Wz = W + (size_t)blockIdx.z * N * K;
  OutT* Cz = C + (size_t)blockIdx.z * M * N;

  const int tid = threadIdx.x;
  const int lane = tid & 63, wid = tid >> 6;
  const int lq = lane & 15, lg = lane >> 4;
  const int wm = wid >> 1, wn = wid & 1;
  const int NT = K >> 6;                  // BK = 64
  const int wb = wid * 1024;              // wave-uniform LDS byte base per call

  const int strow = tid >> 3;             // 0..63
  const int sc8 = (((tid & 7) ^ (strow & 7)) << 3);   // element col 0..56
  const ushort* pa = A + (size_t)(m0 + strow) * K + sc8;
  const ushort* pw = Wz + (size_t)(n0 + strow) * K + sc8;

#define STG_P0(BI, KC) { \
    gload_lds16(pa + (KC), lds + (BI) * BUF + wb); \
    gload_lds16(pa + (size_t)64 * K + (KC), lds + (BI) * BUF + 8192 + wb); \
    gload_lds16(pw + (KC), lds + (BI) * BUF + ABYTES + wb); }
#define STG_P1(BI, KC) { \
    gload_lds16(pa + (size_t)128 * K + (KC), lds + (BI) * BUF + 16384 + wb); \
    gload_lds16(pa + (size_t)192 * K + (KC), lds + (BI) * BUF + 24576 + wb); \
    gload_lds16(pw + (size_t)64 * K + (KC), lds + (BI) * BUF + ABYTES + 8192 + wb); }

  f32x4 acc[4][4];
#pragma unroll
  for (int i = 0; i < 4; i++)
#pragma unroll
    for (int j = 0; j < 4; j++) acc[i][j] = (f32x4){0.f, 0.f, 0.f, 0.f};

  STG_P0(0, 0); STG_P1(0, 0);
  STG_P0(1, 64); STG_P1(1, 64);
  asm volatile("s_waitcnt vmcnt(6)" ::: "memory");
  __builtin_amdgcn_s_barrier();
  __builtin_amdgcn_sched_barrier(0);

  int b = 0, b2 = 2;                      // t%3 and (t+2)%3
  for (int t = 0; t < NT; ++t) {
    const int kc2 = (t + 2) << 6;
    const bool st = (t + 2 < NT);
    const char* bufp = lds + b * BUF;
    short8_t af[4], bfr[4];

    RD_FRAGS(0);
    if (st) STG_P0(b2, kc2);
    MID_SYNC();
    MFMA_ALL();
    END_PHASE();
    __builtin_amdgcn_s_barrier();
    __builtin_amdgcn_sched_barrier(0);

    RD_FRAGS(1);
    if (st) STG_P1(b2, kc2);
    MID_SYNC();
    MFMA_ALL();
    END_PHASE();
    if (st) asm volatile("s_waitcnt vmcnt(6)" ::: "memory");
    else    asm volatile("s_waitcnt vmcnt(0)" ::: "memory");
    __builtin_amdgcn_s_barrier();
    __builtin_amdgcn_sched_barrier(0);
    b = (b == 2) ? 0 : b + 1;
    b2 = (b2 == 2) ? 0 : b2 + 1;
  }

#pragma unroll
  for (int mi = 0; mi < 4; mi++) {
#pragma unroll
    for (int r = 0; r < 4; r++) {
      const int m = m0 + wm * 64 + mi * 16 + lg * 4 + r;
      OutT* cp = Cz + (size_t)m * N + n0 + wn * 64 + lq;
#pragma unroll
      for (int j = 0; j < 4; j++) store_out(cp + j * 16, acc[mi][j][r]);
    }
  }
}

// ---------------------------------------------------------------- RoPE + RMSNorm
// grid (16384, 2): y=0 -> q slab with qnw, y=1 -> k slab with knw. In-place.
__global__ __launch_bounds__(256) void rope_norm_kernel(
    ushort* __restrict__ qk, const float* __restrict__ qnw,
    const float* __restrict__ knw, const float* __restrict__ cosT,
    const float* __restrict__ sinT) {
  const int w = threadIdx.x >> 6, lane = threadIdx.x & 63;
  const float* nw = blockIdx.y ? knw : qnw;
  ushort* base = qk + (size_t)blockIdx.y * MROWS * HID;
  const int rid = blockIdx.x * 4 + w;          // (b*S+s)*NH + h
  const int s = (rid >> 4) & (S_LEN - 1);
  const size_t off = (size_t)rid * HDIM;
  float x1 = bf2f(base[off + lane]);
  float x2 = bf2f(base[off + 64 + lane]);
  float c = cosT[s * 64 + lane], sn = sinT[s * 64 + lane];
  float y1 = x1 * c - x2 * sn;
  float y2 = x2 * c + x1 * sn;
  float ss = y1 * y1 + y2 * y2;
#pragma unroll
  for (int m = 1; m < 64; m <<= 1) ss += __shfl_xor(ss, m, 64);
  float sc = rsqrtf(ss * (1.f / 128.f) + 1e-6f);
  base[off + lane] = f2bf(y1 * sc * nw[lane]);
  base[off + 64 + lane] = f2bf(y2 * sc * nw[lane + 64]);
}

// ---------------------------------------------------------------- flash attention
// Grid 512. XCD-grouped mapping: xcd = bid&7 owns 4 (b,h) heads (K/V working
// set 4 MB = one XCD L2). Each block: q-tile pair {j, 31-j} (66 chunks, exact
// balance). 4 waves x 16 q-rows. Double-buffered KV LDS with depth-1 prefetch:
// chunk i+1's V reg-loads + K gload_lds issued BEFORE chunk i's compute
// (T14 split; one __syncthreads per iteration drains with a full iteration of
// cover). Swapped QK^T; exp2-space softmax with defer-max (THR 11 in log2);
// P stays in registers (sigma-permuted V columns, packed k-pairs).
__global__ __launch_bounds__(256) void attn_kernel(
    const ushort* __restrict__ Q, const ushort* __restrict__ K,
    const ushort* __restrict__ V, ushort* __restrict__ O) {
  __shared__ __align__(16) char LB[2][17408];   // per buf: Ks 8192 | Vt 9216

  const int bid = blockIdx.x;
  const int xcd = bid & 7;
  const int rr  = bid >> 3;              // 0..63
  const int bh  = xcd * 4 + (rr >> 4);   // 0..31, 4 heads per XCD
  const int jj  = rr & 15;
  const int h = bh & 15, b = bh >> 4;
  const int tid = threadIdx.x;
  const int lane = tid & 63, w = tid >> 6;
  const int lq = lane & 15, lg = lane >> 4;

  // K staging geometry (rule-21: linear LDS dest, pre-swizzled global col)
  const int krow0 = w * 8 + (lane >> 4);
  const int krow1 = krow0 + 4;
  const int kc0 = ((lane & 15) * 16) ^ ((krow0 & 7) << 4);
  const int kc1 = ((lane & 15) * 16) ^ ((krow1 & 7) << 4);
  // V staging: thread packs k-pair vp (rows 2vp,2vp+1), d = vd0..vd0+7
  const int vp  = tid & 15;
  const int vd0 = (tid >> 4) * 8;
  const int vc  = (vp < 8) ? ((vp >> 1) * 4 + (vp & 1))
                           : (((vp - 8) >> 1) * 4 + 2 + (vp & 1));
  const float CL2 = 0.12753102368f;      // SCALEF * log2(e)
  const size_t bS = (size_t)b * S_LEN;

  for (int t = 0; t < 2; t++) {
    const int qt = t ? (31 - jj) : jj;
    const int q0 = qt * 64 + w * 16;

    const ushort* qp = Q + (bS + q0 + lq) * HID + h * HDIM + lg * 8;
    short8_t qf[4];
#pragma unroll
    for (int dc = 0; dc < 4; dc++) qf[dc] = *(const short8_t*)(qp + dc * 32);

    f32x4 o[8];
#pragma unroll
    for (int i = 0; i < 8; i++) o[i] = (f32x4){0.f, 0.f, 0.f, 0.f};
    float m_run = -1e30f, l_run = 0.f;
    const int qlim = q0 + 15;
    const int NI = 2 * (qt + 1);         // 32-key chunks

    // prologue: stage chunk 0 into buf 0
    {
      char* Ksb = LB[0];
      uint* Vt = (uint*)(LB[0] + 8192);
      const size_t kbase = bS * HID + h * HDIM;
      const ushort* vsrc = V + kbase + (size_t)(2 * vp) * HID + vd0;
      short8_t va = *(const short8_t*)vsrc;
      short8_t vb = *(const short8_t*)(vsrc + HID);
      gload_lds16(K + kbase + (size_t)krow0 * HID + (kc0 >> 1), Ksb + w * 2048);
      gload_lds16(K + kbase + (size_t)krow1 * HID + (kc1 >> 1), Ksb + w * 2048 + 1024);
#pragma unroll
      for (int e = 0; e < 8; e++)
        Vt[(vd0 + e) * 18 + vc] = (uint)(ushort)va[e] | ((uint)(ushort)vb[e] << 16);
    }
    __syncthreads();

    for (int i = 0; i < NI; ++i) {
      const int cur = i & 1;
      const int k0 = i * 32;
      const char* Ksb = LB[cur];
      const uint* Vt32 = (const uint*)(LB[cur] + 8192);
      char* KsbN = LB[cur ^ 1];
      uint* Vt32N = (uint*)(LB[cur ^ 1] + 8192);
      const bool more = (i + 1 < NI);
      const bool live = (k0 <= qlim);    // wave-uniform

      // prefetch chunk i+1: V reg-loads first, then K gloads (both into buf^1)
      short8_t va, vb;
      if (more) {
        const size_t kbn = (bS + k0 + 32) * HID + h * HDIM;
        const ushort* vsrc = V + kbn + (size_t)(2 * vp) * HID + vd0;
        va = *(const short8_t*)vsrc;
        vb = *(const short8_t*)(vsrc + HID);
        gload_lds16(K + kbn + (size_t)krow0 * HID + (kc0 >> 1), KsbN + w * 2048);
        gload_lds16(K + kbn + (size_t)krow1 * HID + (kc1 >> 1), KsbN + w * 2048 + 1024);
      }

      f32x4 st0 = (f32x4){0.f, 0.f, 0.f, 0.f};
      f32x4 st1 = (f32x4){0.f, 0.f, 0.f, 0.f};
      if (live) {
        __builtin_amdgcn_s_setprio(1);
#pragma unroll
        for (int dc = 0; dc < 4; dc++) {
          const int row0 = lq, row1 = 16 + lq;
          short8_t kf0 = *(const short8_t*)(Ksb + ((row0 * 256 + dc * 64 + lg * 16) ^ ((row0 & 7) << 4)));
          short8_t kf1 = *(const short8_t*)(Ksb + ((row1 * 256 + dc * 64 + lg * 16) ^ ((row1 & 7) << 4)));
          st0 = __builtin_amdgcn_mfma_f32_16x16x32_bf16(kf0, qf[dc], st0, 0, 0, 0);
          st1 = __builtin_amdgcn_mfma_f32_16x16x32_bf16(kf1, qf[dc], st1, 0, 0, 0);
        }
        __builtin_amdgcn_s_setprio(0);
      }

      // write prefetched V into buf^1 (compiler waits the va/vb deps)
      if (more) {
#pragma unroll
        for (int e = 0; e < 8; e++)
          Vt32N[(vd0 + e) * 18 + vc] = (uint)(ushort)va[e] | ((uint)(ushort)vb[e] << 16);
      }

      if (live) {
        const int qg = q0 + lq;
        float sv[8]; float mx = -1e30f;
#pragma unroll
        for (int r = 0; r < 4; r++) {
          const int kk0 = k0 + lg * 4 + r;
          const int kk1 = kk0 + 16;
          float v0 = (kk0 <= qg) ? st0[r] * CL2 : -1e30f;
          float v1 = (kk1 <= qg) ? st1[r] * CL2 : -1e30f;
          sv[r] = v0; sv[4 + r] = v1;
          mx = fmaxf(mx, fmaxf(v0, v1));
        }
        mx = fmaxf(mx, __shfl_xor(mx, 16, 64));
        mx = fmaxf(mx, __shfl_xor(mx, 32, 64));

        float p[8]; float ps = 0.f;
        if (__all(mx <= m_run + 11.0f)) {
#pragma unroll
          for (int u = 0; u < 8; u++) { p[u] = exp2f(sv[u] - m_run); ps += p[u]; }
          ps += __shfl_xor(ps, 16, 64);
          ps += __shfl_xor(ps, 32, 64);
          l_run += ps;
        } else {
          const float m_new = fmaxf(m_run, mx);
          const float alpha = exp2f(m_run - m_new);
#pragma unroll
          for (int u = 0; u < 8; u++) { p[u] = exp2f(sv[u] - m_new); ps += p[u]; }
          ps += __shfl_xor(ps, 16, 64);
          ps += __shfl_xor(ps, 32, 64);
          l_run = l_run * alpha + ps;
          m_run = m_new;
#pragma unroll
          for (int r = 0; r < 4; r++) {
            const float ar = __shfl(alpha, lg * 4 + r, 64);
#pragma unroll
            for (int nt = 0; nt < 8; nt++) o[nt][r] *= ar;
          }
        }

        union { uint u[4]; short8_t s; } pu;
        pu.u[0] = (uint)f2bf(p[0]) | ((uint)f2bf(p[1]) << 16);
        pu.u[1] = (uint)f2bf(p[2]) | ((uint)f2bf(p[3]) << 16);
        pu.u[2] = (uint)f2bf(p[4]) | ((uint)f2bf(p[5]) << 16);
        pu.u[3] = (uint)f2bf(p[6]) | ((uint)f2bf(p[7]) << 16);
        const short8_t pa = pu.s;

        __builtin_amdgcn_s_setprio(1);
#pragma unroll
        for (int nt = 0; nt < 8; nt++) {
          const uint* vq = &Vt32[(nt * 16 + lq) * 18 + lg * 4];
          uint2 vlo = *(const uint2*)vq;
          uint2 vhi = *(const uint2*)(vq + 2);
          union { uint u[4]; short8_t s; } vu;
          vu.u[0] = vlo.x; vu.u[1] = vlo.y; vu.u[2] = vhi.x; vu.u[3] = vhi.y;
          o[nt] = __builtin_amdgcn_mfma_f32_16x16x32_bf16(pa, vu.s, o[nt], 0, 0, 0);
        }
        __builtin_amdgcn_s_setprio(0);
      }

      __syncthreads();                    // buf^1 ready; buf reads complete
    }

    const float invl = (l_run > 0.f) ? 1.f / l_run : 0.f;
#pragma unroll
    for (int r = 0; r < 4; r++) {
      const float iv = __shfl(invl, lg * 4 + r, 64);
      ushort* op = O + (bS + q0 + lg * 4 + r) * HID + h * HDIM + lq;
#pragma unroll
      for (int nt = 0; nt < 8; nt++) op[nt * 16] = f2bf(o[nt][r] * iv);
    }
  }
}

// ---------------------------------------------------------------- launcher
extern "C" void kernel_launch(void* const* d_in, const int* in_sizes, int n_in,
                              void* d_out, int out_size, void* d_ws, size_t ws_size,
                              hipStream_t stream) {
  const float* x   = (const float*)d_in[0];
  const float* wq  = (const float*)d_in[1];
  const float* wk  = (const float*)d_in[2];
  const float* wv  = (const float*)d_in[3];
  const float* wo  = (const float*)d_in[4];
  const float* qnw = (const float*)d_in[5];
  const float* knw = (const float*)d_in[6];
  float* out = (float*)d_out;
  char* ws = (char*)d_ws;

  const size_t NELEM = (size_t)MROWS * HID;       // 8388608
  const size_t WELEM = (size_t)HID * HID;         // 4194304

  ushort* xb    = (ushort*)(ws);                          // 16777216 B
  ushort* wqkvb = (ushort*)(ws + 16777216);               // 25165824 B
  ushort* wob   = (ushort*)(ws + 41943040);               //  8388608 B
  ushort* qkv   = (ushort*)(ws + 50331648);               // 50331648 B (q,k,v)
  float*  cosT  = (float*)(ws + 100663296);               //   524288 B
  float*  sinT  = (float*)(ws + 101187584);               //   524288 B
  ushort* attnb = xb;                                     // alias (xb dead after QKV)

  cast_all_kernel<<<2048, 256, 0, stream>>>(x, wq, wk, wv, wo, xb, wqkvb, wob);
  rope_tab_kernel<<<512, 256, 0, stream>>>(cosT, sinT);

  // QKV = x @ {wq,wk,wv}^T (bf16 out): BM=256 x BN=128, 768 blocks = 3x256 CUs
  gemm_pipe_kernel<ushort><<<dim3(16, 16, 3), 512, 0, stream>>>(
      xb, wqkvb, qkv, MROWS, HID, HID);

  // fused RoPE + per-head RMSNorm on q and k (in-place)
  rope_norm_kernel<<<dim3(16384, 2), 256, 0, stream>>>(qkv, qnw, knw, cosT, sinT);

  // attention: 512 blocks x 256 threads, XCD-grouped heads, KV prefetch
  attn_kernel<<<512, 256, 0, stream>>>(qkv, qkv + NELEM, qkv + 2 * NELEM, attnb);

  // out = attn @ wo^T (fp32 out): 256 blocks = 1x256 CUs
  gemm_pipe_kernel<float><<<dim3(16, 16, 1), 512, 0, stream>>>(
      attnb, wob, out, MROWS, HID, HID);
}

// Round 9
// 275.556 us; speedup vs baseline: 1.1870x; 1.1416x over previous
//
#include <hip/hip_runtime.h>
#include <hip/hip_bf16.h>

// B=2, S=2048, HID=2048, NH=16, HD=128.
// fused cast->bf16, QKV GEMM (BM256xBN128xBK64, 3-buffer depth-2 counted-vmcnt
// pipeline), rope tables, fused rope+rmsnorm (in-place; q pre-scaled by
// SCALE*log2e), flash attention (64-key iterations, fixed-shift exp2 softmax
// with NO max tracking -- legal because RMSNorm bounds |s*CL2| < 16.5 --
// deferred l-reduce, KV prefetch, XCD-grouped heads), projection GEMM.

typedef __attribute__((ext_vector_type(8))) short short8_t;   // 8 x bf16
typedef __attribute__((ext_vector_type(4))) short short4_t;
typedef __attribute__((ext_vector_type(4))) float f32x4;

#define S_LEN 2048
#define NHEAD 16
#define HDIM  128
#define HID   2048
#define MROWS 4096            // B*S
#define SCALEF 0.08838834764831845f

__device__ __forceinline__ float bf2f(ushort u) {
  union { unsigned int u; float f; } a; a.u = ((unsigned int)u) << 16; return a.f;
}
__device__ __forceinline__ ushort f2bf(float f) {
  union { float f; unsigned int u; } a; a.f = f;
  unsigned int r = a.u + 0x7FFFu + ((a.u >> 16) & 1u);
  return (ushort)(r >> 16);
}
__device__ __forceinline__ void store_out(ushort* p, float v) { *p = f2bf(v); }
__device__ __forceinline__ void store_out(float* p, float v) { *p = v; }

// async global->LDS, 16B per lane; LDS dest must be wave-uniform (HW adds lane*16).
__device__ __forceinline__ void gload_lds16(const void* g, void* l) {
  __builtin_amdgcn_global_load_lds(
      (const __attribute__((address_space(1))) unsigned int*)g,
      (__attribute__((address_space(3))) unsigned int*)l, 16, 0, 0);
}

// ---------------------------------------------------------------- fused casts
__global__ __launch_bounds__(256) void cast_all_kernel(
    const float* __restrict__ x, const float* __restrict__ wq,
    const float* __restrict__ wk, const float* __restrict__ wv,
    const float* __restrict__ wo, ushort* __restrict__ xb,
    ushort* __restrict__ wqkvb, ushort* __restrict__ wob) {
  int i = blockIdx.x * 256 + threadIdx.x;
  const int stride = gridDim.x * 256;
  for (; i < 6291456; i += stride) {
    const float4* src; short4_t* dst; int off;
    if (i < 2097152)      { src = (const float4*)x;  dst = (short4_t*)xb;               off = i; }
    else if (i < 3145728) { src = (const float4*)wq; dst = (short4_t*)wqkvb;            off = i - 2097152; }
    else if (i < 4194304) { src = (const float4*)wk; dst = (short4_t*)wqkvb + 1048576;  off = i - 3145728; }
    else if (i < 5242880) { src = (const float4*)wv; dst = (short4_t*)wqkvb + 2097152;  off = i - 4194304; }
    else                  { src = (const float4*)wo; dst = (short4_t*)wob;              off = i - 5242880; }
    float4 v = src[off];
    short4_t o = { (short)f2bf(v.x), (short)f2bf(v.y),
                   (short)f2bf(v.z), (short)f2bf(v.w) };
    dst[off] = o;
  }
}

// ---------------------------------------------------------------- rope tables
__global__ __launch_bounds__(256) void rope_tab_kernel(
    float* __restrict__ cosT, float* __restrict__ sinT) {
  int idx = blockIdx.x * 256 + threadIdx.x;
  if (idx >= S_LEN * 64) return;
  int s = idx >> 6, i = idx & 63;
  float f = expf(9.2103403719761836f * (float)(2 * i));
  float inv = 1.0f / f;                 // inf -> 0, matches reference
  float ang = (float)s * inv;
  cosT[idx] = cosf(ang);
  sinT[idx] = sinf(ang);
}

// ---------------------------------------------------------------- pipelined GEMM
// (unchanged round-6 winner: BM=256 x BN=128, BK=64, 3 buffers, depth-2
// counted vmcnt, conflict-free XOR swizzle — 0 bank conflicts measured)
#define RD_FRAGS(KK) \
  _Pragma("unroll") for (int j = 0; j < 4; ++j) { \
    const int rw = wn * 64 + j * 16 + lq; \
    bfr[j] = *(const short8_t*)(bufp + ABYTES + rw * 128 + \
                                ((((KK) * 4 + lg) ^ (rw & 7)) << 4)); } \
  _Pragma("unroll") for (int i = 0; i < 4; ++i) { \
    const int rw = wm * 64 + i * 16 + lq; \
    af[i] = *(const short8_t*)(bufp + rw * 128 + \
                               ((((KK) * 4 + lg) ^ (rw & 7)) << 4)); }
#define MFMA_ALL() _Pragma("unroll") for (int i = 0; i < 4; ++i) \
    _Pragma("unroll") for (int j = 0; j < 4; ++j) \
      acc[i][j] = __builtin_amdgcn_mfma_f32_16x16x32_bf16( \
          af[i], bfr[j], acc[i][j], 0, 0, 0);
#define MID_SYNC() \
    __builtin_amdgcn_s_barrier(); \
    asm volatile("s_waitcnt lgkmcnt(0)" ::: "memory"); \
    __builtin_amdgcn_sched_barrier(0); \
    __builtin_amdgcn_s_setprio(1);
#define END_PHASE() \
    __builtin_amdgcn_s_setprio(0);

template <typename OutT>
__global__ __launch_bounds__(512, 2) void gemm_pipe_kernel(
    const ushort* __restrict__ A, const ushort* __restrict__ W,
    OutT* __restrict__ C, int M, int N, int K) {
  constexpr int ABYTES = 32768;           // A bytes per buffer (256 x 128B)
  constexpr int BUF = 49152;              // A + B (128 x 128B)
  __shared__ __align__(16) char lds[3 * BUF];   // 147456 B

  const int n0 = blockIdx.x * 128;
  const int m0 = blockIdx.y * 256;
  const ushort* Wz = W + (size_t)blockIdx.z * N * K;
  OutT* Cz = C + (size_t)blockIdx.z * M * N;

  const int tid = threadIdx.x;
  const int lane = tid & 63, wid = tid >> 6;
  const int lq = lane & 15, lg = lane >> 4;
  const int wm = wid >> 1, wn = wid & 1;
  const int NT = K >> 6;                  // BK = 64
  const int wb = wid * 1024;              // wave-uniform LDS byte base per call

  const int strow = tid >> 3;             // 0..63
  const int sc8 = (((tid & 7) ^ (strow & 7)) << 3);   // element col 0..56
  const ushort* pa = A + (size_t)(m0 + strow) * K + sc8;
  const ushort* pw = Wz + (size_t)(n0 + strow) * K + sc8;

#define STG_P0(BI, KC) { \
    gload_lds16(pa + (KC), lds + (BI) * BUF + wb); \
    gload_lds16(pa + (size_t)64 * K + (KC), lds + (BI) * BUF + 8192 + wb); \
    gload_lds16(pw + (KC), lds + (BI) * BUF + ABYTES + wb); }
#define STG_P1(BI, KC) { \
    gload_lds16(pa + (size_t)128 * K + (KC), lds + (BI) * BUF + 16384 + wb); \
    gload_lds16(pa + (size_t)192 * K + (KC), lds + (BI) * BUF + 24576 + wb); \
    gload_lds16(pw + (size_t)64 * K + (KC), lds + (BI) * BUF + ABYTES + 8192 + wb); }

  f32x4 acc[4][4];
#pragma unroll
  for (int i = 0; i < 4; i++)
#pragma unroll
    for (int j = 0; j < 4; j++) acc[i][j] = (f32x4){0.f, 0.f, 0.f, 0.f};

  STG_P0(0, 0); STG_P1(0, 0);
  STG_P0(1, 64); STG_P1(1, 64);
  asm volatile("s_waitcnt vmcnt(6)" ::: "memory");
  __builtin_amdgcn_s_barrier();
  __builtin_amdgcn_sched_barrier(0);

  int b = 0, b2 = 2;                      // t%3 and (t+2)%3
  for (int t = 0; t < NT; ++t) {
    const int kc2 = (t + 2) << 6;
    const bool st = (t + 2 < NT);
    const char* bufp = lds + b * BUF;
    short8_t af[4], bfr[4];

    RD_FRAGS(0);
    if (st) STG_P0(b2, kc2);
    MID_SYNC();
    MFMA_ALL();
    END_PHASE();
    __builtin_amdgcn_s_barrier();
    __builtin_amdgcn_sched_barrier(0);

    RD_FRAGS(1);
    if (st) STG_P1(b2, kc2);
    MID_SYNC();
    MFMA_ALL();
    END_PHASE();
    if (st) asm volatile("s_waitcnt vmcnt(6)" ::: "memory");
    else    asm volatile("s_waitcnt vmcnt(0)" ::: "memory");
    __builtin_amdgcn_s_barrier();
    __builtin_amdgcn_sched_barrier(0);
    b = (b == 2) ? 0 : b + 1;
    b2 = (b2 == 2) ? 0 : b2 + 1;
  }

#pragma unroll
  for (int mi = 0; mi < 4; mi++) {
#pragma unroll
    for (int r = 0; r < 4; r++) {
      const int m = m0 + wm * 64 + mi * 16 + lg * 4 + r;
      OutT* cp = Cz + (size_t)m * N + n0 + wn * 64 + lq;
#pragma unroll
      for (int j = 0; j < 4; j++) store_out(cp + j * 16, acc[mi][j][r]);
    }
  }
}

// ---------------------------------------------------------------- RoPE + RMSNorm
// grid (16384, 2): y=0 -> q slab (output pre-scaled by SCALE*log2e for the
// fixed-shift exp2 softmax), y=1 -> k slab. In-place.
__global__ __launch_bounds__(256) void rope_norm_kernel(
    ushort* __restrict__ qk, const float* __restrict__ qnw,
    const float* __restrict__ knw, const float* __restrict__ cosT,
    const float* __restrict__ sinT) {
  const int w = threadIdx.x >> 6, lane = threadIdx.x & 63;
  const float* nw = blockIdx.y ? knw : qnw;
  const float oscale = blockIdx.y ? 1.0f : 0.12753102368f;   // SCALE*log2(e)
  ushort* base = qk + (size_t)blockIdx.y * MROWS * HID;
  const int rid = blockIdx.x * 4 + w;          // (b*S+s)*NH + h
  const int s = (rid >> 4) & (S_LEN - 1);
  const size_t off = (size_t)rid * HDIM;
  float x1 = bf2f(base[off + lane]);
  float x2 = bf2f(base[off + 64 + lane]);
  float c = cosT[s * 64 + lane], sn = sinT[s * 64 + lane];
  float y1 = x1 * c - x2 * sn;
  float y2 = x2 * c + x1 * sn;
  float ss = y1 * y1 + y2 * y2;
#pragma unroll
  for (int m = 1; m < 64; m <<= 1) ss += __shfl_xor(ss, m, 64);
  float sc = rsqrtf(ss * (1.f / 128.f) + 1e-6f) * oscale;
  base[off + lane] = f2bf(y1 * sc * nw[lane]);
  base[off + 64 + lane] = f2bf(y2 * sc * nw[lane + 64]);
}

// ---------------------------------------------------------------- flash attention
// Grid 512, XCD-grouped heads (K/V set = 4 MB per XCD L2; FETCH 25 MB measured).
// Block: q-tile pair {j, 31-j} -> uniform 33 iterations of 64 keys. 4 waves x
// 16 q-rows. Double-buffered KV (2 x 34 KB), depth-1 prefetch (T14).
// FIXED-SHIFT softmax: q pre-scaled by SCALE*log2e and RMSNorm bounds
// |s| <= 16.5, so p = exp2(s) <= 2^16.5 fits fp32/bf16 with NO max tracking,
// no rescale, no per-chunk cross-lane reduce (l reduced once per tile).
// P packed via v_cvt_pk_bf16_f32; V packed via v_perm_b32; sigma-permuted
// V columns so P never leaves registers.
__global__ __launch_bounds__(256) void attn_kernel(
    const ushort* __restrict__ Q, const ushort* __restrict__ K,
    const ushort* __restrict__ V, ushort* __restrict__ O) {
  // per buffer: Ks 64x256B = 16384 | Vt half0 [128][18]u32 = 9216 | half1 9216
  __shared__ __align__(16) char LB[2][34816];

  const int bid = blockIdx.x;
  const int xcd = bid & 7;
  const int rr  = bid >> 3;              // 0..63
  const int bh  = xcd * 4 + (rr >> 4);   // 4 heads per XCD
  const int jj  = rr & 15;
  const int h = bh & 15, b = bh >> 4;
  const int tid = threadIdx.x;
  const int lane = tid & 63, w = tid >> 6;
  const int lq = lane & 15, lg = lane >> 4;

  // V staging: thread packs pair-col vp (keys 2vp,2vp+1 of each 32-half), d rows vd0..vd0+7
  const int vp  = tid & 15;
  const int vd0 = (tid >> 4) * 8;
  const int vc  = (vp < 8) ? ((vp >> 1) * 4 + (vp & 1))
                           : (((vp - 8) >> 1) * 4 + 2 + (vp & 1));
  const size_t bS = (size_t)b * S_LEN;

  union S8U4 { short8_t s; uint u[4]; };

#define STAGE_K64(DST, KBASE) _Pragma("unroll") for (int c = 0; c < 4; ++c) { \
    const int kr = w * 16 + c * 4 + (lane >> 4); \
    const int kc = ((lane & 15) * 16) ^ ((kr & 7) << 4); \
    gload_lds16(K + (KBASE) + (size_t)kr * HID + (kc >> 1), (DST) + w * 4096 + c * 1024); }

#define STAGE_V_LOAD(KBASE) { \
    const ushort* vs = V + (KBASE) + (size_t)(2 * vp) * HID + vd0; \
    va0.s = *(const short8_t*)vs;            vb0.s = *(const short8_t*)(vs + HID); \
    va1.s = *(const short8_t*)(vs + 32 * HID); vb1.s = *(const short8_t*)(vs + 33 * HID); }

#define STAGE_V_WRITE(VT0, VT1) \
    _Pragma("unroll") for (int j = 0; j < 4; ++j) { \
      (VT0)[(vd0 + 2 * j) * 18 + vc]     = __builtin_amdgcn_perm(vb0.u[j], va0.u[j], 0x05040100u); \
      (VT0)[(vd0 + 2 * j + 1) * 18 + vc] = __builtin_amdgcn_perm(vb0.u[j], va0.u[j], 0x07060302u); \
      (VT1)[(vd0 + 2 * j) * 18 + vc]     = __builtin_amdgcn_perm(vb1.u[j], va1.u[j], 0x05040100u); \
      (VT1)[(vd0 + 2 * j + 1) * 18 + vc] = __builtin_amdgcn_perm(vb1.u[j], va1.u[j], 0x07060302u); }

  for (int t = 0; t < 2; t++) {
    const int qt = t ? (31 - jj) : jj;
    const int q0 = qt * 64 + w * 16;
    const int qg = q0 + lq;

    const ushort* qp = Q + (bS + q0 + lq) * HID + h * HDIM + lg * 8;
    short8_t qf[4];
#pragma unroll
    for (int dc = 0; dc < 4; dc++) qf[dc] = *(const short8_t*)(qp + dc * 32);

    f32x4 o[8];
#pragma unroll
    for (int i = 0; i < 8; i++) o[i] = (f32x4){0.f, 0.f, 0.f, 0.f};
    float l_run = 0.f;
    const int NI = qt + 1;               // 64-key iterations

    // prologue: stage chunk 0 into buf 0
    {
      S8U4 va0, vb0, va1, vb1;
      uint* Vt0 = (uint*)(LB[0] + 16384);
      uint* Vt1 = (uint*)(LB[0] + 25600);
      const size_t kb0 = bS * HID + h * HDIM;
      STAGE_V_LOAD(kb0);
      STAGE_K64(LB[0], kb0);
      STAGE_V_WRITE(Vt0, Vt1);
    }
    __syncthreads();

    for (int i = 0; i < NI; ++i) {
      const int cur = i & 1;
      const int k0 = i * 64;
      const char* Ksb = LB[cur];
      const uint* Vt0 = (const uint*)(LB[cur] + 16384);
      const uint* Vt1 = (const uint*)(LB[cur] + 25600);
      char* KsbN = LB[cur ^ 1];
      uint* VtN0 = (uint*)(LB[cur ^ 1] + 16384);
      uint* VtN1 = (uint*)(LB[cur ^ 1] + 25600);
      const bool more = (i + 1 < NI);

      // prefetch i+1 (T14: issue early, write late)
      S8U4 va0, vb0, va1, vb1;
      if (more) {
        const size_t kbn = (bS + k0 + 64) * HID + h * HDIM;
        STAGE_V_LOAD(kbn);
        STAGE_K64(KsbN, kbn);
      }

      // QK^T: st[kb] reg r = s[key k0+kb*16+lg*4+r][q0+lq]  (q pre-scaled CL2)
      f32x4 st[4];
#pragma unroll
      for (int kb = 0; kb < 4; ++kb) st[kb] = (f32x4){0.f, 0.f, 0.f, 0.f};
      __builtin_amdgcn_s_setprio(1);
#pragma unroll
      for (int dc = 0; dc < 4; ++dc)
#pragma unroll
        for (int kb = 0; kb < 4; ++kb) {
          const int row = kb * 16 + lq;
          short8_t kf = *(const short8_t*)(Ksb + ((row * 256 + dc * 64 + lg * 16) ^ ((row & 7) << 4)));
          st[kb] = __builtin_amdgcn_mfma_f32_16x16x32_bf16(kf, qf[dc], st[kb], 0, 0, 0);
        }
      __builtin_amdgcn_s_setprio(0);

      // write prefetched V into next buffer (vmcnt dep handled by compiler)
      if (more) STAGE_V_WRITE(VtN0, VtN1);

      // fixed-shift softmax: p = exp2(s), masked -> 0; l accumulates per-lane
      float p[16]; float ps = 0.f;
#pragma unroll
      for (int kb = 0; kb < 4; ++kb)
#pragma unroll
        for (int r = 0; r < 4; ++r) {
          const int kk = k0 + kb * 16 + lg * 4 + r;
          const float e = exp2f((kk <= qg) ? st[kb][r] : -1e30f);
          p[kb * 4 + r] = e;
          ps += e;
        }
      l_run += ps;

      uint pk[8];
#pragma unroll
      for (int j = 0; j < 8; ++j)
        asm("v_cvt_pk_bf16_f32 %0, %1, %2" : "=v"(pk[j]) : "v"(p[2 * j]), "v"(p[2 * j + 1]));
      union { uint u[4]; short8_t s; } P0, P1;
      P0.u[0] = pk[0]; P0.u[1] = pk[1]; P0.u[2] = pk[2]; P0.u[3] = pk[3];
      P1.u[0] = pk[4]; P1.u[1] = pk[5]; P1.u[2] = pk[6]; P1.u[3] = pk[7];

      __builtin_amdgcn_s_setprio(1);
#pragma unroll
      for (int nt = 0; nt < 8; nt++) {
        const uint* vq0 = &Vt0[(nt * 16 + lq) * 18 + lg * 4];
        const uint* vq1 = &Vt1[(nt * 16 + lq) * 18 + lg * 4];
        uint2 a0 = *(const uint2*)vq0, a1 = *(const uint2*)(vq0 + 2);
        uint2 b0v = *(const uint2*)vq1, b1v = *(const uint2*)(vq1 + 2);
        union { uint u[4]; short8_t s; } V0, V1;
        V0.u[0] = a0.x; V0.u[1] = a0.y; V0.u[2] = a1.x; V0.u[3] = a1.y;
        V1.u[0] = b0v.x; V1.u[1] = b0v.y; V1.u[2] = b1v.x; V1.u[3] = b1v.y;
        o[nt] = __builtin_amdgcn_mfma_f32_16x16x32_bf16(P0.s, V0.s, o[nt], 0, 0, 0);
        o[nt] = __builtin_amdgcn_mfma_f32_16x16x32_bf16(P1.s, V1.s, o[nt], 0, 0, 0);
      }
      __builtin_amdgcn_s_setprio(0);

      __syncthreads();                    // next buf ready; cur reads complete
    }

    // deferred l reduce (once per tile) + output
    float lf = l_run;
    lf += __shfl_xor(lf, 16, 64);
    lf += __shfl_xor(lf, 32, 64);
    const float invl = 1.f / lf;          // diagonal key always live -> lf > 0
#pragma unroll
    for (int r = 0; r < 4; r++) {
      const float iv = __shfl(invl, lg * 4 + r, 64);
      ushort* op = O + (bS + q0 + lg * 4 + r) * HID + h * HDIM + lq;
#pragma unroll
      for (int nt = 0; nt < 8; nt++) op[nt * 16] = f2bf(o[nt][r] * iv);
    }
    __syncthreads();                      // protect LB[0] reuse by next tile
  }
}

// ---------------------------------------------------------------- launcher
extern "C" void kernel_launch(void* const* d_in, const int* in_sizes, int n_in,
                              void* d_out, int out_size, void* d_ws, size_t ws_size,
                              hipStream_t stream) {
  const float* x   = (const float*)d_in[0];
  const float* wq  = (const float*)d_in[1];
  const float* wk  = (const float*)d_in[2];
  const float* wv  = (const float*)d_in[3];
  const float* wo  = (const float*)d_in[4];
  const float* qnw = (const float*)d_in[5];
  const float* knw = (const float*)d_in[6];
  float* out = (float*)d_out;
  char* ws = (char*)d_ws;

  const size_t NELEM = (size_t)MROWS * HID;       // 8388608
  const size_t WELEM = (size_t)HID * HID;         // 4194304

  ushort* xb    = (ushort*)(ws);                          // 16777216 B
  ushort* wqkvb = (ushort*)(ws + 16777216);               // 25165824 B
  ushort* wob   = (ushort*)(ws + 41943040);               //  8388608 B
  ushort* qkv   = (ushort*)(ws + 50331648);               // 50331648 B (q,k,v)
  float*  cosT  = (float*)(ws + 100663296);               //   524288 B
  float*  sinT  = (float*)(ws + 101187584);               //   524288 B
  ushort* attnb = xb;                                     // alias (xb dead after QKV)

  cast_all_kernel<<<2048, 256, 0, stream>>>(x, wq, wk, wv, wo, xb, wqkvb, wob);
  rope_tab_kernel<<<512, 256, 0, stream>>>(cosT, sinT);

  // QKV = x @ {wq,wk,wv}^T (bf16 out): BM=256 x BN=128, 768 blocks = 3x256 CUs
  gemm_pipe_kernel<ushort><<<dim3(16, 16, 3), 512, 0, stream>>>(
      xb, wqkvb, qkv, MROWS, HID, HID);

  // fused RoPE + per-head RMSNorm on q and k (in-place; q gets CL2 fold)
  rope_norm_kernel<<<dim3(16384, 2), 256, 0, stream>>>(qkv, qnw, knw, cosT, sinT);

  // attention: 512 blocks x 256 threads, XCD-grouped heads, 64-key iterations
  attn_kernel<<<512, 256, 0, stream>>>(qkv, qkv + NELEM, qkv + 2 * NELEM, attnb);

  // out = attn @ wo^T (fp32 out): 256 blocks = 1x256 CUs
  gemm_pipe_kernel<float><<<dim3(16, 16, 1), 512, 0, stream>>>(
      attnb, wob, out, MROWS, HID, HID);
}

// Round 10
// 261.694 us; speedup vs baseline: 1.2499x; 1.0530x over previous
//
#include <hip/hip_runtime.h>
#include <hip/hip_bf16.h>

// B=2, S=2048, HID=2048, NH=16, HD=128.
// fused cast->bf16, QKV GEMM (BM256xBN128xBK64, 3-buffer depth-2 counted-vmcnt
// pipeline, XCD-rectangular grid swizzle, FUSED rope+rmsnorm epilogue on q/k
// slabs), rope tables, flash attention (64-key iterations, fixed-shift exp2
// softmax, deferred l-reduce, KV prefetch, XCD-grouped heads), projection GEMM.

typedef __attribute__((ext_vector_type(8))) short short8_t;   // 8 x bf16
typedef __attribute__((ext_vector_type(4))) short short4_t;
typedef __attribute__((ext_vector_type(4))) float f32x4;

#define S_LEN 2048
#define NHEAD 16
#define HDIM  128
#define HID   2048
#define MROWS 4096            // B*S
#define SCALEF 0.08838834764831845f

__device__ __forceinline__ float bf2f(ushort u) {
  union { unsigned int u; float f; } a; a.u = ((unsigned int)u) << 16; return a.f;
}
__device__ __forceinline__ ushort f2bf(float f) {
  union { float f; unsigned int u; } a; a.f = f;
  unsigned int r = a.u + 0x7FFFu + ((a.u >> 16) & 1u);
  return (ushort)(r >> 16);
}
__device__ __forceinline__ void store_out(ushort* p, float v) { *p = f2bf(v); }
__device__ __forceinline__ void store_out(float* p, float v) { *p = v; }

// async global->LDS, 16B per lane; LDS dest must be wave-uniform (HW adds lane*16).
__device__ __forceinline__ void gload_lds16(const void* g, void* l) {
  __builtin_amdgcn_global_load_lds(
      (const __attribute__((address_space(1))) unsigned int*)g,
      (__attribute__((address_space(3))) unsigned int*)l, 16, 0, 0);
}

// ---------------------------------------------------------------- fused casts
__global__ __launch_bounds__(256) void cast_all_kernel(
    const float* __restrict__ x, const float* __restrict__ wq,
    const float* __restrict__ wk, const float* __restrict__ wv,
    const float* __restrict__ wo, ushort* __restrict__ xb,
    ushort* __restrict__ wqkvb, ushort* __restrict__ wob) {
  int i = blockIdx.x * 256 + threadIdx.x;
  const int stride = gridDim.x * 256;
  for (; i < 6291456; i += stride) {
    const float4* src; short4_t* dst; int off;
    if (i < 2097152)      { src = (const float4*)x;  dst = (short4_t*)xb;               off = i; }
    else if (i < 3145728) { src = (const float4*)wq; dst = (short4_t*)wqkvb;            off = i - 2097152; }
    else if (i < 4194304) { src = (const float4*)wk; dst = (short4_t*)wqkvb + 1048576;  off = i - 3145728; }
    else if (i < 5242880) { src = (const float4*)wv; dst = (short4_t*)wqkvb + 2097152;  off = i - 4194304; }
    else                  { src = (const float4*)wo; dst = (short4_t*)wob;              off = i - 5242880; }
    float4 v = src[off];
    short4_t o = { (short)f2bf(v.x), (short)f2bf(v.y),
                   (short)f2bf(v.z), (short)f2bf(v.w) };
    dst[off] = o;
  }
}

// ---------------------------------------------------------------- rope tables
__global__ __launch_bounds__(256) void rope_tab_kernel(
    float* __restrict__ cosT, float* __restrict__ sinT) {
  int idx = blockIdx.x * 256 + threadIdx.x;
  if (idx >= S_LEN * 64) return;
  int s = idx >> 6, i = idx & 63;
  float f = expf(9.2103403719761836f * (float)(2 * i));
  float inv = 1.0f / f;                 // inf -> 0, matches reference
  float ang = (float)s * inv;
  cosT[idx] = cosf(ang);
  sinT[idx] = sinf(ang);
}

// ---------------------------------------------------------------- pipelined GEMM
// Round-6 core (BM=256 x BN=128, BK=64, 3 buffers, depth-2 counted vmcnt,
// conflict-free XOR swizzle) + two additions:
//  * XCD-rectangular grid swizzle: dispatch idx mod 8 = XCD; XCD c owns a
//    4n x 8m rectangle -> per-XCD L2 working set ~10 MB instead of ~17 MB.
//  * ROPE epilogue (q/k slabs): C-tile is head-aligned (128 cols = one head),
//    so RoPE + per-head RMSNorm fuse here: stage bf16 C in LDS, one barrier,
//    per-row (2 threads/row) rope+norm, write final q/k. Identical numerics
//    to the old separate kernel (same bf16 rounding point).
#define RD_FRAGS(KK) \
  _Pragma("unroll") for (int j = 0; j < 4; ++j) { \
    const int rw = wn * 64 + j * 16 + lq; \
    bfr[j] = *(const short8_t*)(bufp + ABYTES + rw * 128 + \
                                ((((KK) * 4 + lg) ^ (rw & 7)) << 4)); } \
  _Pragma("unroll") for (int i = 0; i < 4; ++i) { \
    const int rw = wm * 64 + i * 16 + lq; \
    af[i] = *(const short8_t*)(bufp + rw * 128 + \
                               ((((KK) * 4 + lg) ^ (rw & 7)) << 4)); }
#define MFMA_ALL() _Pragma("unroll") for (int i = 0; i < 4; ++i) \
    _Pragma("unroll") for (int j = 0; j < 4; ++j) \
      acc[i][j] = __builtin_amdgcn_mfma_f32_16x16x32_bf16( \
          af[i], bfr[j], acc[i][j], 0, 0, 0);
#define MID_SYNC() \
    __builtin_amdgcn_s_barrier(); \
    asm volatile("s_waitcnt lgkmcnt(0)" ::: "memory"); \
    __builtin_amdgcn_sched_barrier(0); \
    __builtin_amdgcn_s_setprio(1);
#define END_PHASE() \
    __builtin_amdgcn_s_setprio(0);

template <typename OutT, bool ROPE>
__global__ __launch_bounds__(512, 2) void gemm_pipe_kernel(
    const ushort* __restrict__ A, const ushort* __restrict__ W,
    OutT* __restrict__ C, int M, int N, int K,
    const float* __restrict__ qnw, const float* __restrict__ knw,
    const float* __restrict__ cosT, const float* __restrict__ sinT) {
  constexpr int ABYTES = 32768;           // A bytes per buffer (256 x 128B)
  constexpr int BUF = 49152;              // A + B (128 x 128B)
  __shared__ __align__(16) char lds[3 * BUF];   // 147456 B

  // XCD-rectangular swizzle (grids are 16x16): c = dispatch&7 owns 4n x 8m.
  const int flat = blockIdx.y * 16 + blockIdx.x;
  const int xc = flat & 7, xr = flat >> 3;          // xr in 0..31
  const int n0 = ((xc & 3) * 4 + (xr & 3)) * 128;
  const int m0 = ((xc >> 2) * 8 + (xr >> 2)) * 256;
  const ushort* Wz = W + (size_t)blockIdx.z * N * K;
  OutT* Cz = C + (size_t)blockIdx.z * M * N;

  const int tid = threadIdx.x;
  const int lane = tid & 63, wid = tid >> 6;
  const int lq = lane & 15, lg = lane >> 4;
  const int wm = wid >> 1, wn = wid & 1;
  const int NT = K >> 6;                  // BK = 64
  const int wb = wid * 1024;              // wave-uniform LDS byte base per call

  const int strow = tid >> 3;             // 0..63
  const int sc8 = (((tid & 7) ^ (strow & 7)) << 3);   // element col 0..56
  const ushort* pa = A + (size_t)(m0 + strow) * K + sc8;
  const ushort* pw = Wz + (size_t)(n0 + strow) * K + sc8;

#define STG_P0(BI, KC) { \
    gload_lds16(pa + (KC), lds + (BI) * BUF + wb); \
    gload_lds16(pa + (size_t)64 * K + (KC), lds + (BI) * BUF + 8192 + wb); \
    gload_lds16(pw + (KC), lds + (BI) * BUF + ABYTES + wb); }
#define STG_P1(BI, KC) { \
    gload_lds16(pa + (size_t)128 * K + (KC), lds + (BI) * BUF + 16384 + wb); \
    gload_lds16(pa + (size_t)192 * K + (KC), lds + (BI) * BUF + 24576 + wb); \
    gload_lds16(pw + (size_t)64 * K + (KC), lds + (BI) * BUF + ABYTES + 8192 + wb); }

  f32x4 acc[4][4];
#pragma unroll
  for (int i = 0; i < 4; i++)
#pragma unroll
    for (int j = 0; j < 4; j++) acc[i][j] = (f32x4){0.f, 0.f, 0.f, 0.f};

  STG_P0(0, 0); STG_P1(0, 0);
  STG_P0(1, 64); STG_P1(1, 64);
  asm volatile("s_waitcnt vmcnt(6)" ::: "memory");
  __builtin_amdgcn_s_barrier();
  __builtin_amdgcn_sched_barrier(0);

  int b = 0, b2 = 2;                      // t%3 and (t+2)%3
  for (int t = 0; t < NT; ++t) {
    const int kc2 = (t + 2) << 6;
    const bool st = (t + 2 < NT);
    const char* bufp = lds + b * BUF;
    short8_t af[4], bfr[4];

    RD_FRAGS(0);
    if (st) STG_P0(b2, kc2);
    MID_SYNC();
    MFMA_ALL();
    END_PHASE();
    __builtin_amdgcn_s_barrier();
    __builtin_amdgcn_sched_barrier(0);

    RD_FRAGS(1);
    if (st) STG_P1(b2, kc2);
    MID_SYNC();
    MFMA_ALL();
    END_PHASE();
    if (st) asm volatile("s_waitcnt vmcnt(6)" ::: "memory");
    else    asm volatile("s_waitcnt vmcnt(0)" ::: "memory");
    __builtin_amdgcn_s_barrier();
    __builtin_amdgcn_sched_barrier(0);
    b = (b == 2) ? 0 : b + 1;
    b2 = (b2 == 2) ? 0 : b2 + 1;
  }

  if constexpr (ROPE) {
    if (blockIdx.z < 2) {
      // ---- fused RoPE + per-head RMSNorm epilogue (q: z=0, k: z=1) ----
      const float* nw = (blockIdx.z == 0) ? qnw : knw;
      const float oscale = (blockIdx.z == 0) ? 0.12753102368f : 1.0f; // CL2 fold
      ushort* CT = (ushort*)lds;          // [256][134] bf16, 68.6 KB
#pragma unroll
      for (int mi = 0; mi < 4; mi++)
#pragma unroll
        for (int r = 0; r < 4; r++) {
          const int row = wm * 64 + mi * 16 + lg * 4 + r;
#pragma unroll
          for (int j = 0; j < 4; j++)
            CT[row * 134 + wn * 64 + j * 16 + lq] = f2bf(acc[mi][j][r]);
        }
      __syncthreads();
      const int row = tid >> 1;
      const int i0 = (tid & 1) * 32;      // rope-pair index range
      const int m = m0 + row;
      const int s = m & (S_LEN - 1);
      float y1[32], y2[32];
      float ss = 0.f;
#pragma unroll
      for (int cu = 0; cu < 4; ++cu) {
        short8_t x1v = *(const short8_t*)&CT[row * 134 + i0 + cu * 8];
        short8_t x2v = *(const short8_t*)&CT[row * 134 + 64 + i0 + cu * 8];
#pragma unroll
        for (int e = 0; e < 8; ++e) {
          const int i = i0 + cu * 8 + e;
          const float c = cosT[s * 64 + i], sn = sinT[s * 64 + i];
          const float x1 = bf2f((ushort)x1v[e]);
          const float x2 = bf2f((ushort)x2v[e]);
          y1[cu * 8 + e] = x1 * c - x2 * sn;
          y2[cu * 8 + e] = x2 * c + x1 * sn;
          ss += y1[cu * 8 + e] * y1[cu * 8 + e] + y2[cu * 8 + e] * y2[cu * 8 + e];
        }
      }
      ss += __shfl_xor(ss, 1, 64);        // pair (tid, tid^1) shares the row
      const float sc = rsqrtf(ss * (1.f / 128.f) + 1e-6f) * oscale;
      ushort* gp = (ushort*)Cz + (size_t)m * N + n0;
#pragma unroll
      for (int cu = 0; cu < 4; ++cu) {
        short8_t o1, o2;
#pragma unroll
        for (int e = 0; e < 8; ++e) {
          const int i = i0 + cu * 8 + e;
          o1[e] = (short)f2bf(y1[cu * 8 + e] * sc * nw[i]);
          o2[e] = (short)f2bf(y2[cu * 8 + e] * sc * nw[i + 64]);
        }
        *(short8_t*)&gp[i0 + cu * 8] = o1;
        *(short8_t*)&gp[i0 + 64 + cu * 8] = o2;
      }
      return;
    }
  }

#pragma unroll
  for (int mi = 0; mi < 4; mi++) {
#pragma unroll
    for (int r = 0; r < 4; r++) {
      const int m = m0 + wm * 64 + mi * 16 + lg * 4 + r;
      OutT* cp = Cz + (size_t)m * N + n0 + wn * 64 + lq;
#pragma unroll
      for (int j = 0; j < 4; j++) store_out(cp + j * 16, acc[mi][j][r]);
    }
  }
}

// ---------------------------------------------------------------- flash attention
// Grid 512, XCD-grouped heads (K/V set = 4 MB per XCD L2; FETCH 25 MB measured).
// Block: q-tile pair {j, 31-j} -> uniform 33 iterations of 64 keys. 4 waves x
// 16 q-rows. Double-buffered KV (2 x 34 KB), depth-1 prefetch (T14).
// FIXED-SHIFT softmax: q pre-scaled by SCALE*log2e and RMSNorm bounds
// |s| <= 16.5, so p = exp2(s) <= 2^16.5 fits fp32/bf16 with NO max tracking,
// no rescale, no per-chunk cross-lane reduce (l reduced once per tile).
__global__ __launch_bounds__(256) void attn_kernel(
    const ushort* __restrict__ Q, const ushort* __restrict__ K,
    const ushort* __restrict__ V, ushort* __restrict__ O) {
  // per buffer: Ks 64x256B = 16384 | Vt half0 [128][18]u32 = 9216 | half1 9216
  __shared__ __align__(16) char LB[2][34816];

  const int bid = blockIdx.x;
  const int xcd = bid & 7;
  const int rr  = bid >> 3;              // 0..63
  const int bh  = xcd * 4 + (rr >> 4);   // 4 heads per XCD
  const int jj  = rr & 15;
  const int h = bh & 15, b = bh >> 4;
  const int tid = threadIdx.x;
  const int lane = tid & 63, w = tid >> 6;
  const int lq = lane & 15, lg = lane >> 4;

  const int vp  = tid & 15;
  const int vd0 = (tid >> 4) * 8;
  const int vc  = (vp < 8) ? ((vp >> 1) * 4 + (vp & 1))
                           : (((vp - 8) >> 1) * 4 + 2 + (vp & 1));
  const size_t bS = (size_t)b * S_LEN;

  union S8U4 { short8_t s; uint u[4]; };

#define STAGE_K64(DST, KBASE) _Pragma("unroll") for (int c = 0; c < 4; ++c) { \
    const int kr = w * 16 + c * 4 + (lane >> 4); \
    const int kc = ((lane & 15) * 16) ^ ((kr & 7) << 4); \
    gload_lds16(K + (KBASE) + (size_t)kr * HID + (kc >> 1), (DST) + w * 4096 + c * 1024); }

#define STAGE_V_LOAD(KBASE) { \
    const ushort* vs = V + (KBASE) + (size_t)(2 * vp) * HID + vd0; \
    va0.s = *(const short8_t*)vs;            vb0.s = *(const short8_t*)(vs + HID); \
    va1.s = *(const short8_t*)(vs + 32 * HID); vb1.s = *(const short8_t*)(vs + 33 * HID); }

#define STAGE_V_WRITE(VT0, VT1) \
    _Pragma("unroll") for (int j = 0; j < 4; ++j) { \
      (VT0)[(vd0 + 2 * j) * 18 + vc]     = __builtin_amdgcn_perm(vb0.u[j], va0.u[j], 0x05040100u); \
      (VT0)[(vd0 + 2 * j + 1) * 18 + vc] = __builtin_amdgcn_perm(vb0.u[j], va0.u[j], 0x07060302u); \
      (VT1)[(vd0 + 2 * j) * 18 + vc]     = __builtin_amdgcn_perm(vb1.u[j], va1.u[j], 0x05040100u); \
      (VT1)[(vd0 + 2 * j + 1) * 18 + vc] = __builtin_amdgcn_perm(vb1.u[j], va1.u[j], 0x07060302u); }

  for (int t = 0; t < 2; t++) {
    const int qt = t ? (31 - jj) : jj;
    const int q0 = qt * 64 + w * 16;
    const int qg = q0 + lq;

    const ushort* qp = Q + (bS + q0 + lq) * HID + h * HDIM + lg * 8;
    short8_t qf[4];
#pragma unroll
    for (int dc = 0; dc < 4; dc++) qf[dc] = *(const short8_t*)(qp + dc * 32);

    f32x4 o[8];
#pragma unroll
    for (int i = 0; i < 8; i++) o[i] = (f32x4){0.f, 0.f, 0.f, 0.f};
    float l_run = 0.f;
    const int NI = qt + 1;               // 64-key iterations

    {
      S8U4 va0, vb0, va1, vb1;
      uint* Vt0 = (uint*)(LB[0] + 16384);
      uint* Vt1 = (uint*)(LB[0] + 25600);
      const size_t kb0 = bS * HID + h * HDIM;
      STAGE_V_LOAD(kb0);
      STAGE_K64(LB[0], kb0);
      STAGE_V_WRITE(Vt0, Vt1);
    }
    __syncthreads();

    for (int i = 0; i < NI; ++i) {
      const int cur = i & 1;
      const int k0 = i * 64;
      const char* Ksb = LB[cur];
      const uint* Vt0 = (const uint*)(LB[cur] + 16384);
      const uint* Vt1 = (const uint*)(LB[cur] + 25600);
      char* KsbN = LB[cur ^ 1];
      uint* VtN0 = (uint*)(LB[cur ^ 1] + 16384);
      uint* VtN1 = (uint*)(LB[cur ^ 1] + 25600);
      const bool more = (i + 1 < NI);

      S8U4 va0, vb0, va1, vb1;
      if (more) {
        const size_t kbn = (bS + k0 + 64) * HID + h * HDIM;
        STAGE_V_LOAD(kbn);
        STAGE_K64(KsbN, kbn);
      }

      f32x4 st[4];
#pragma unroll
      for (int kb = 0; kb < 4; ++kb) st[kb] = (f32x4){0.f, 0.f, 0.f, 0.f};
      __builtin_amdgcn_s_setprio(1);
#pragma unroll
      for (int dc = 0; dc < 4; ++dc)
#pragma unroll
        for (int kb = 0; kb < 4; ++kb) {
          const int row = kb * 16 + lq;
          short8_t kf = *(const short8_t*)(Ksb + ((row * 256 + dc * 64 + lg * 16) ^ ((row & 7) << 4)));
          st[kb] = __builtin_amdgcn_mfma_f32_16x16x32_bf16(kf, qf[dc], st[kb], 0, 0, 0);
        }
      __builtin_amdgcn_s_setprio(0);

      if (more) STAGE_V_WRITE(VtN0, VtN1);

      float p[16]; float ps = 0.f;
#pragma unroll
      for (int kb = 0; kb < 4; ++kb)
#pragma unroll
        for (int r = 0; r < 4; ++r) {
          const int kk = k0 + kb * 16 + lg * 4 + r;
          const float e = exp2f((kk <= qg) ? st[kb][r] : -1e30f);
          p[kb * 4 + r] = e;
          ps += e;
        }
      l_run += ps;

      uint pk[8];
#pragma unroll
      for (int j = 0; j < 8; ++j)
        asm("v_cvt_pk_bf16_f32 %0, %1, %2" : "=v"(pk[j]) : "v"(p[2 * j]), "v"(p[2 * j + 1]));
      union { uint u[4]; short8_t s; } P0, P1;
      P0.u[0] = pk[0]; P0.u[1] = pk[1]; P0.u[2] = pk[2]; P0.u[3] = pk[3];
      P1.u[0] = pk[4]; P1.u[1] = pk[5]; P1.u[2] = pk[6]; P1.u[3] = pk[7];

      __builtin_amdgcn_s_setprio(1);
#pragma unroll
      for (int nt = 0; nt < 8; nt++) {
        const uint* vq0 = &Vt0[(nt * 16 + lq) * 18 + lg * 4];
        const uint* vq1 = &Vt1[(nt * 16 + lq) * 18 + lg * 4];
        uint2 a0 = *(const uint2*)vq0, a1 = *(const uint2*)(vq0 + 2);
        uint2 b0v = *(const uint2*)vq1, b1v = *(const uint2*)(vq1 + 2);
        union { uint u[4]; short8_t s; } V0, V1;
        V0.u[0] = a0.x; V0.u[1] = a0.y; V0.u[2] = a1.x; V0.u[3] = a1.y;
        V1.u[0] = b0v.x; V1.u[1] = b0v.y; V1.u[2] = b1v.x; V1.u[3] = b1v.y;
        o[nt] = __builtin_amdgcn_mfma_f32_16x16x32_bf16(P0.s, V0.s, o[nt], 0, 0, 0);
        o[nt] = __builtin_amdgcn_mfma_f32_16x16x32_bf16(P1.s, V1.s, o[nt], 0, 0, 0);
      }
      __builtin_amdgcn_s_setprio(0);

      __syncthreads();
    }

    float lf = l_run;
    lf += __shfl_xor(lf, 16, 64);
    lf += __shfl_xor(lf, 32, 64);
    const float invl = 1.f / lf;
#pragma unroll
    for (int r = 0; r < 4; r++) {
      const float iv = __shfl(invl, lg * 4 + r, 64);
      ushort* op = O + (bS + q0 + lg * 4 + r) * HID + h * HDIM + lq;
#pragma unroll
      for (int nt = 0; nt < 8; nt++) op[nt * 16] = f2bf(o[nt][r] * iv);
    }
    __syncthreads();
  }
}

// ---------------------------------------------------------------- launcher
extern "C" void kernel_launch(void* const* d_in, const int* in_sizes, int n_in,
                              void* d_out, int out_size, void* d_ws, size_t ws_size,
                              hipStream_t stream) {
  const float* x   = (const float*)d_in[0];
  const float* wq  = (const float*)d_in[1];
  const float* wk  = (const float*)d_in[2];
  const float* wv  = (const float*)d_in[3];
  const float* wo  = (const float*)d_in[4];
  const float* qnw = (const float*)d_in[5];
  const float* knw = (const float*)d_in[6];
  float* out = (float*)d_out;
  char* ws = (char*)d_ws;

  const size_t NELEM = (size_t)MROWS * HID;       // 8388608
  const size_t WELEM = (size_t)HID * HID;         // 4194304

  ushort* xb    = (ushort*)(ws);                          // 16777216 B
  ushort* wqkvb = (ushort*)(ws + 16777216);               // 25165824 B
  ushort* wob   = (ushort*)(ws + 41943040);               //  8388608 B
  ushort* qkv   = (ushort*)(ws + 50331648);               // 50331648 B (q,k,v)
  float*  cosT  = (float*)(ws + 100663296);               //   524288 B
  float*  sinT  = (float*)(ws + 101187584);               //   524288 B
  ushort* attnb = xb;                                     // alias (xb dead after QKV)

  cast_all_kernel<<<2048, 256, 0, stream>>>(x, wq, wk, wv, wo, xb, wqkvb, wob);
  rope_tab_kernel<<<512, 256, 0, stream>>>(cosT, sinT);

  // QKV = x @ {wq,wk,wv}^T with fused rope+rmsnorm epilogue on q/k slabs
  gemm_pipe_kernel<ushort, true><<<dim3(16, 16, 3), 512, 0, stream>>>(
      xb, wqkvb, qkv, MROWS, HID, HID, qnw, knw, cosT, sinT);

  // attention: 512 blocks x 256 threads, XCD-grouped heads, 64-key iterations
  attn_kernel<<<512, 256, 0, stream>>>(qkv, qkv + NELEM, qkv + 2 * NELEM, attnb);

  // out = attn @ wo^T (fp32 out): 256 blocks = 1x256 CUs
  gemm_pipe_kernel<float, false><<<dim3(16, 16, 1), 512, 0, stream>>>(
      attnb, wob, out, MROWS, HID, HID, nullptr, nullptr, nullptr, nullptr);
}